// Round 1
// 440.079 us; speedup vs baseline: 1.2134x; 1.2134x over previous
//
#include <hip/hip_runtime.h>
#include <hip/hip_bf16.h>

typedef __bf16 bf16x8 __attribute__((ext_vector_type(8)));
typedef __bf16 bf16x4 __attribute__((ext_vector_type(4)));
typedef float  f32x4  __attribute__((ext_vector_type(4)));

// tanh(x) = 1 - 2/(exp(2x)+1); native v_exp + v_rcp (no IEEE div expansion).
// rcp is ~1 ulp; saturation exact: rcp(inf)=0 -> +1, exp->0 -> -1.
__device__ __forceinline__ float fast_tanh(float x) {
    float e = __expf(2.0f * x);
    float r = __builtin_amdgcn_rcpf(e + 1.0f);
    return __builtin_fmaf(-2.0f, r, 1.0f);
}

// Convert fp32 weights to bf16, TRANSPOSED to [n][k]: each lane's MFMA
// A-operand fragment (8 consecutive k at fixed n) is one contiguous 16B load.
__global__ void prep_weights(const float* __restrict__ W1,
                             const float* __restrict__ W2,
                             const float* __restrict__ W3,
                             __bf16* __restrict__ w1t,   // [256][64]
                             __bf16* __restrict__ w2t,   // [256][256]
                             __bf16* __restrict__ w3t) { // [64][256]
    int idx = blockIdx.x * blockDim.x + threadIdx.x;
    if (idx < 64 * 256) {                 // W1 [k=64][n=256] -> W1T[n][k]
        int n = idx >> 6, k = idx & 63;
        w1t[idx] = (__bf16)W1[k * 256 + n];
    }
    int i2 = idx - 64 * 256;
    if (i2 >= 0 && i2 < 256 * 256) {      // W2 [k=256][n=256] -> W2T[n][k]
        int n = i2 >> 8, k = i2 & 255;
        w2t[i2] = (__bf16)W2[k * 256 + n];
    }
    int i3 = idx - 64 * 256 - 256 * 256;  // W3 [k=256][n=64] -> W3T[n][k]
    if (i3 >= 0 && i3 < 64 * 256) {
        int n = i3 >> 8, k = i3 & 255;
        w3t[i3] = (__bf16)W3[k * 64 + n];
    }
}

// One block = 16 batch rows for ALL time steps. 512 threads = 8 waves.
// OPERAND-SWAPPED MFMA: A = weight (W^T[n][k]), B = activation (h[m][k]).
// D comes out [n][m]: lane holds 4 CONSECUTIVE n at fixed batch row m
// -> vectorized b64 LDS writes, 2-way-max bank pattern (free).
__global__ __launch_bounds__(512, 2)
void ode_kernel(const float* __restrict__ x0,
                const float* __restrict__ b1,
                const float* __restrict__ b2,
                const float* __restrict__ b3,
                const float* __restrict__ dt_scale,
                const int*   __restrict__ num_steps,
                const __bf16* __restrict__ w1t,
                const __bf16* __restrict__ w2t,
                const __bf16* __restrict__ w3t,
                float* __restrict__ out) {
    __shared__ float  xs[16][68];    // fp32 state; stride 68 -> col access conflict-free
    __shared__ __bf16 xb[16][72];    // bf16 copy for GEMM1 B-frags
    __shared__ __bf16 h1[16][264];   // tanh(xW1+b1); stride 132 words = 4 mod 32
    __shared__ __bf16 h2[16][264];

    const int tid  = threadIdx.x;
    const int wave = tid >> 6;
    const int lane = tid & 63;
    const int q    = lane >> 4;      // quad: k-block of frags / n-subblock of D
    const int c    = lane & 15;      // n for A-frag(weight), m(batch row) for B-frag & D
    const int row0 = blockIdx.x * 16;

    const float scale = dt_scale[0] * 0.01f;   // dt_scale * DT
    const int   nT    = num_steps[0];

    // ---- one-time weight fragment loads (A-operand layout, [n][k]) ----
    bf16x8 w1f[2][2];                 // [kt][nt], n = wave*32 + nt*16 + c
    #pragma unroll
    for (int kt = 0; kt < 2; ++kt)
        #pragma unroll
        for (int nt = 0; nt < 2; ++nt) {
            int n = wave * 32 + nt * 16 + c;
            w1f[kt][nt] = *(const bf16x8*)(w1t + n * 64 + kt * 32 + q * 8);
        }
    bf16x8 w2f[8][2];
    #pragma unroll
    for (int kt = 0; kt < 8; ++kt)
        #pragma unroll
        for (int nt = 0; nt < 2; ++nt) {
            int n = wave * 32 + nt * 16 + c;
            w2f[kt][nt] = *(const bf16x8*)(w2t + n * 256 + kt * 32 + q * 8);
        }
    bf16x8 w3f[8];
    f32x4  b3v4 = (f32x4){0.f, 0.f, 0.f, 0.f};
    if (wave < 4) {
        int n = wave * 16 + c;
        #pragma unroll
        for (int kt = 0; kt < 8; ++kt)
            w3f[kt] = *(const bf16x8*)(w3t + n * 256 + kt * 32 + q * 8);
        b3v4 = *(const f32x4*)(b3 + wave * 16 + q * 4);   // n = w*16 + q*4 + r
    }
    f32x4 b1v4[2], b2v4[2];
    #pragma unroll
    for (int nt = 0; nt < 2; ++nt) {
        b1v4[nt] = *(const f32x4*)(b1 + wave * 32 + nt * 16 + q * 4);
        b2v4[nt] = *(const f32x4*)(b2 + wave * 32 + nt * 16 + q * 4);
    }

    // ---- load x0 into LDS state, emit t=0 trajectory slice ----
    const int mio = tid >> 5, sio = (tid & 31) * 2;
    float* outp = out + ((size_t)(row0 + mio) * 201) * 64 + sio;
    {
        const float2 v = *(const float2*)(x0 + (size_t)(row0 + mio) * 64 + sio);
        xs[mio][sio]     = v.x;  xs[mio][sio + 1] = v.y;
        xb[mio][sio]     = (__bf16)v.x;
        xb[mio][sio + 1] = (__bf16)v.y;
        *(float2*)outp = v;
        outp += 64;
    }
    __syncthreads();

    for (int t = 0; t < nT; ++t) {
        // GEMM1: h1 = tanh(x @ W1 + b1)   D[n][m], lane: m=c, n=base+q*4+r
        {
            f32x4 acc[2] = {b1v4[0], b1v4[1]};
            #pragma unroll
            for (int kt = 0; kt < 2; ++kt) {
                bf16x8 a = *(const bf16x8*)(&xb[c][kt * 32 + q * 8]);
                acc[0] = __builtin_amdgcn_mfma_f32_16x16x32_bf16(w1f[kt][0], a, acc[0], 0, 0, 0);
                acc[1] = __builtin_amdgcn_mfma_f32_16x16x32_bf16(w1f[kt][1], a, acc[1], 0, 0, 0);
            }
            #pragma unroll
            for (int nt = 0; nt < 2; ++nt) {
                bf16x4 o;
                #pragma unroll
                for (int r = 0; r < 4; ++r) o[r] = (__bf16)fast_tanh(acc[nt][r]);
                *(bf16x4*)(&h1[c][wave * 32 + nt * 16 + q * 4]) = o;
            }
        }
        __syncthreads();

        // GEMM2: h2 = tanh(h1 @ W2 + b2); two independent 4-deep acc chains
        {
            f32x4 acc[2]  = {b2v4[0], b2v4[1]};
            f32x4 accB[2] = {(f32x4){0,0,0,0}, (f32x4){0,0,0,0}};
            #pragma unroll
            for (int kt = 0; kt < 4; ++kt) {
                bf16x8 a0 = *(const bf16x8*)(&h1[c][kt * 32 + q * 8]);
                bf16x8 a1 = *(const bf16x8*)(&h1[c][(kt + 4) * 32 + q * 8]);
                acc[0]  = __builtin_amdgcn_mfma_f32_16x16x32_bf16(w2f[kt][0],     a0, acc[0],  0, 0, 0);
                acc[1]  = __builtin_amdgcn_mfma_f32_16x16x32_bf16(w2f[kt][1],     a0, acc[1],  0, 0, 0);
                accB[0] = __builtin_amdgcn_mfma_f32_16x16x32_bf16(w2f[kt + 4][0], a1, accB[0], 0, 0, 0);
                accB[1] = __builtin_amdgcn_mfma_f32_16x16x32_bf16(w2f[kt + 4][1], a1, accB[1], 0, 0, 0);
            }
            #pragma unroll
            for (int nt = 0; nt < 2; ++nt) {
                f32x4 s = acc[nt] + accB[nt];
                bf16x4 o;
                #pragma unroll
                for (int r = 0; r < 4; ++r) o[r] = (__bf16)fast_tanh(s[r]);
                *(bf16x4*)(&h2[c][wave * 32 + nt * 16 + q * 4]) = o;
            }
        }
        __syncthreads();

        // GEMM3: dx = h2 @ W3 + b3; x += dx*scale  (waves 0..3; vectorized RMW)
        if (wave < 4) {
            f32x4 acc  = b3v4;
            f32x4 accB = (f32x4){0, 0, 0, 0};
            #pragma unroll
            for (int kt = 0; kt < 4; ++kt) {
                bf16x8 a0 = *(const bf16x8*)(&h2[c][kt * 32 + q * 8]);
                bf16x8 a1 = *(const bf16x8*)(&h2[c][(kt + 4) * 32 + q * 8]);
                acc  = __builtin_amdgcn_mfma_f32_16x16x32_bf16(w3f[kt],     a0, acc,  0, 0, 0);
                accB = __builtin_amdgcn_mfma_f32_16x16x32_bf16(w3f[kt + 4], a1, accB, 0, 0, 0);
            }
            acc += accB;
            f32x4 xv = *(f32x4*)(&xs[c][wave * 16 + q * 4]);
            xv += acc * scale;
            *(f32x4*)(&xs[c][wave * 16 + q * 4]) = xv;
            bf16x4 xbv;
            #pragma unroll
            for (int r = 0; r < 4; ++r) xbv[r] = (__bf16)xv[r];
            *(bf16x4*)(&xb[c][wave * 16 + q * 4]) = xbv;
        }
        __syncthreads();

        // trajectory store (coalesced float2); overlaps next GEMM1
        {
            float2 v = *(const float2*)(&xs[mio][sio]);
            *(float2*)outp = v;
            outp += 64;
        }
    }
}

extern "C" void kernel_launch(void* const* d_in, const int* in_sizes, int n_in,
                              void* d_out, int out_size, void* d_ws, size_t ws_size,
                              hipStream_t stream) {
    const float* x0 = (const float*)d_in[0];
    const float* W1 = (const float*)d_in[1];
    const float* b1 = (const float*)d_in[2];
    const float* W2 = (const float*)d_in[3];
    const float* b2 = (const float*)d_in[4];
    const float* W3 = (const float*)d_in[5];
    const float* b3 = (const float*)d_in[6];
    const float* dt = (const float*)d_in[7];
    const int*   ns = (const int*)d_in[8];

    __bf16* w1t = (__bf16*)d_ws;           // 16384 bf16
    __bf16* w2t = w1t + 64 * 256;          // 65536 bf16
    __bf16* w3t = w2t + 256 * 256;         // 16384 bf16

    prep_weights<<<384, 256, 0, stream>>>(W1, W2, W3, w1t, w2t, w3t);

    int rows = in_sizes[0] / 64;           // 4096
    ode_kernel<<<rows / 16, 512, 0, stream>>>(x0, b1, b2, b3, dt, ns,
                                              w1t, w2t, w3t, (float*)d_out);
}